// Round 2
// baseline (249.756 us; speedup 1.0000x reference)
//
#include <hip/hip_runtime.h>
#include <hip/hip_bf16.h>
#include <stdint.h>

// Problem constants (all inputs & output are FP32 per the reference file)
#define BATCH 128
#define LAT   2000
#define NG    10000
#define KW    20
#define OUTW  (NG * KW)   // 200000
#define EPSV  1e-5f

// Tiling: block tile = 128 batch x 32 groups; 313 blocks (>256 CUs)
#define GT     32
#define BK     64
#define KITERS 32   // 2000 zero-padded to 2048

typedef __bf16 bf16x8 __attribute__((ext_vector_type(8)));
typedef float  f32x4  __attribute__((ext_vector_type(4)));

__device__ __forceinline__ ushort f2bf(float f) {
  uint32_t u = __builtin_bit_cast(uint32_t, f);
  u = (u + 0x7FFFu + ((u >> 16) & 1u)) >> 16;  // RNE
  return (ushort)u;
}

__device__ __forceinline__ int4 pack8(const float* p) {
  float4 f0 = *(const float4*)p;
  float4 f1 = *(const float4*)(p + 4);
  int4 v;
  v.x = (int)((uint32_t)f2bf(f0.x) | ((uint32_t)f2bf(f0.y) << 16));
  v.y = (int)((uint32_t)f2bf(f0.z) | ((uint32_t)f2bf(f0.w) << 16));
  v.z = (int)((uint32_t)f2bf(f1.x) | ((uint32_t)f2bf(f1.y) << 16));
  v.w = (int)((uint32_t)f2bf(f1.z) | ((uint32_t)f2bf(f1.w) << 16));
  return v;
}

// Fused: GEMM (z @ W^T, bf16 MFMA) + BatchNorm(batch,training) + LeakyReLU
// + per-group outer-product expand (x20) + LeakyReLU + sigmoid -> fp32 out.
// b_fc is skipped: BN subtracts the batch mean immediately after the linear,
// so the per-group bias cancels exactly.
// Block: 256 thr = 4 waves as 2(m) x 2(n); wave tile 64 rows x 16 groups
// (4 m-tiles x 1 n-tile of 16x16x32 bf16 MFMA).
__global__ __launch_bounds__(256, 2) void fused_decoder_kernel(
    const float* __restrict__ zp, const float* __restrict__ wp,
    const float* __restrict__ gammap, const float* __restrict__ betap,
    const float* __restrict__ convwp, const float* __restrict__ convbp,
    float* __restrict__ out) {
  const int tid = threadIdx.x;
  const int g0  = blockIdx.x * GT;

  // LDS tiles, row stride 64 bf16 (128 B), 16B-chunk XOR-by-row swizzle:
  // chunk s of row r lives at r*64 + ((s ^ (r&7))*8) ushorts -> conflict-free
  // ds_read_b128 / ds_write_b128.
  __shared__ ushort As[BATCH * BK];     // 16 KB
  __shared__ ushort Bs[GT * BK];        //  4 KB
  __shared__ float statS[2][2][16];     // [wm][wn][col]
  __shared__ float statQ[2][2][16];

  const int lane = tid & 63;
  const int w    = tid >> 6;
  const int wm   = w & 1;      // M half: rows wm*64 ..
  const int wn   = w >> 1;     // N half: cols wn*16 ..
  const int q    = lane >> 4;  // quad 0..3
  const int cl   = lane & 15;

  f32x4 acc[4];
  const f32x4 vzero = {0.f, 0.f, 0.f, 0.f};
#pragma unroll
  for (int i = 0; i < 4; ++i) acc[i] = vzero;

  for (int it = 0; it < KITERS; ++it) {
    const int k0 = it * BK;
    __syncthreads();  // previous iteration's readers done

    // ---- stage A (z tile): 128 rows x 8 chunks of 8 elems = 1024 chunks ----
#pragma unroll
    for (int i = 0; i < 4; ++i) {
      int c = i * 256 + tid;
      int r = c >> 3, s = c & 7;
      int gk = k0 + s * 8;
      int4 v = make_int4(0, 0, 0, 0);
      if (gk < LAT)  // LAT % 8 == 0: chunk fully valid or fully padding
        v = pack8(zp + (size_t)r * LAT + gk);
      *(int4*)&As[r * BK + ((s ^ (r & 7)) << 3)] = v;
    }
    // ---- stage B (W tile): 32 rows x 8 chunks = 256 chunks ----
    {
      int r = tid >> 3, s = tid & 7;
      int g  = g0 + r;
      int gk = k0 + s * 8;
      int4 v = make_int4(0, 0, 0, 0);
      if (gk < LAT && g < NG)
        v = pack8(wp + (size_t)g * LAT + gk);
      *(int4*)&Bs[r * BK + ((s ^ (r & 7)) << 3)] = v;
    }
    __syncthreads();

    // ---- MFMA: A[m=lane&15][k=q*8+j], B[n=lane&15][k=q*8+j] ----
#pragma unroll
    for (int kk = 0; kk < 2; ++kk) {
      int s = kk * 4 + q;
      bf16x8 af[4], bfr;
#pragma unroll
      for (int mt = 0; mt < 4; ++mt) {
        int ra = wm * 64 + mt * 16 + cl;
        af[mt] = *(const bf16x8*)&As[ra * BK + ((s ^ (ra & 7)) << 3)];
      }
      {
        int rb = wn * 16 + cl;
        bfr = *(const bf16x8*)&Bs[rb * BK + ((s ^ (rb & 7)) << 3)];
      }
#pragma unroll
      for (int mt = 0; mt < 4; ++mt)
        acc[mt] = __builtin_amdgcn_mfma_f32_16x16x32_bf16(af[mt], bfr,
                                                          acc[mt], 0, 0, 0);
    }
  }

  // ---- BatchNorm stats: D layout col=lane&15, row=(lane>>4)*4+reg ----
  float s = 0.f, ss = 0.f;
#pragma unroll
  for (int mt = 0; mt < 4; ++mt)
#pragma unroll
    for (int r = 0; r < 4; ++r) {
      float v = acc[mt][r];
      s += v;
      ss += v * v;
    }
  s += __shfl_xor(s, 16); ss += __shfl_xor(ss, 16);
  s += __shfl_xor(s, 32); ss += __shfl_xor(ss, 32);
  if (q == 0) { statS[wm][wn][cl] = s; statQ[wm][wn][cl] = ss; }
  __syncthreads();

  // ---- Epilogue: BN + leaky + (h*w[k]+cb) + leaky + sigmoid -> fp32 ----
  const int gcol = g0 + wn * 16 + cl;
  const int gc   = (gcol < NG) ? gcol : (NG - 1);  // clamp for safe loads
  float S = statS[0][wn][cl] + statS[1][wn][cl];
  float Q = statQ[0][wn][cl] + statQ[1][wn][cl];
  float mean = S * (1.f / 128.f);
  float var  = Q * (1.f / 128.f) - mean * mean;
  var = (var < 0.f) ? 0.f : var;
  float inv = __builtin_amdgcn_rsqf(var + EPSV);

  float ga = gammap[gc], be = betap[gc], cb = convbp[gc];
  float wv[KW];
  {
    const float4* pw = (const float4*)(convwp + (size_t)gc * KW);
#pragma unroll
    for (int j = 0; j < 5; ++j) {
      float4 f = pw[j];
      wv[4 * j] = f.x; wv[4 * j + 1] = f.y;
      wv[4 * j + 2] = f.z; wv[4 * j + 3] = f.w;
    }
  }
  float scale = inv * ga;
  float shift = be - mean * scale;
  const bool ok = (gcol < NG);

#pragma unroll
  for (int mt = 0; mt < 4; ++mt) {
#pragma unroll
    for (int r = 0; r < 4; ++r) {
      float h = acc[mt][r] * scale + shift;
      h = fmaxf(h, h * 0.1f);  // leaky(0.1): slope<1 => max(x, 0.1x)
      int b = wm * 64 + mt * 16 + q * 4 + r;
      float4 ov[5];
#pragma unroll
      for (int j = 0; j < 5; ++j) {
        float y0 = h * wv[4 * j]     + cb;
        float y1 = h * wv[4 * j + 1] + cb;
        float y2 = h * wv[4 * j + 2] + cb;
        float y3 = h * wv[4 * j + 3] + cb;
        y0 = fmaxf(y0, y0 * 0.1f);
        y1 = fmaxf(y1, y1 * 0.1f);
        y2 = fmaxf(y2, y2 * 0.1f);
        y3 = fmaxf(y3, y3 * 0.1f);
        ov[j].x = __builtin_amdgcn_rcpf(1.f + exp2f(y0 * -1.44269504f));
        ov[j].y = __builtin_amdgcn_rcpf(1.f + exp2f(y1 * -1.44269504f));
        ov[j].z = __builtin_amdgcn_rcpf(1.f + exp2f(y2 * -1.44269504f));
        ov[j].w = __builtin_amdgcn_rcpf(1.f + exp2f(y3 * -1.44269504f));
      }
      if (ok) {
        float4* po = (float4*)(out + (size_t)b * OUTW + (size_t)gcol * KW);
#pragma unroll
        for (int j = 0; j < 5; ++j) po[j] = ov[j];
      }
    }
  }
}

extern "C" void kernel_launch(void* const* d_in, const int* in_sizes, int n_in,
                              void* d_out, int out_size, void* d_ws, size_t ws_size,
                              hipStream_t stream) {
  const float* z     = (const float*)d_in[0];
  const float* W     = (const float*)d_in[1];
  // d_in[2] = b_fc: unused — cancels under training-mode batchnorm
  const float* gamma = (const float*)d_in[3];
  const float* beta  = (const float*)d_in[4];
  const float* convw = (const float*)d_in[5];
  const float* convb = (const float*)d_in[6];
  float* out = (float*)d_out;

  dim3 grid((NG + GT - 1) / GT);  // 313 blocks
  fused_decoder_kernel<<<grid, 256, 0, stream>>>(z, W, gamma, beta, convw,
                                                 convb, out);
}

// Round 3
// 225.080 us; speedup vs baseline: 1.1096x; 1.1096x over previous
//
#include <hip/hip_runtime.h>
#include <hip/hip_bf16.h>
#include <stdint.h>

// Problem constants (all inputs & output are FP32 per the reference file)
#define BATCH 128
#define LAT   2000
#define NG    10000
#define KW    20
#define OUTW  (NG * KW)   // 200000
#define EPSV  1e-5f

// ---- Phase 1 (GEMM) tiling: block tile = 64 groups x 128 batch, split-K=4
#define GT    64
#define BK    64
#define KSPL  4
// split k-lengths: 512,512,512,464 (all multiples of 8)

typedef __bf16 bf16x8 __attribute__((ext_vector_type(8)));
typedef float  f32x4  __attribute__((ext_vector_type(4)));

__device__ __forceinline__ ushort f2bf(float f) {
  uint32_t u = __builtin_bit_cast(uint32_t, f);
  u = (u + 0x7FFFu + ((u >> 16) & 1u)) >> 16;  // RNE
  return (ushort)u;
}

__device__ __forceinline__ int4 pack8(const float* p) {
  float4 f0 = *(const float4*)p;
  float4 f1 = *(const float4*)(p + 4);
  int4 v;
  v.x = (int)((uint32_t)f2bf(f0.x) | ((uint32_t)f2bf(f0.y) << 16));
  v.y = (int)((uint32_t)f2bf(f0.z) | ((uint32_t)f2bf(f0.w) << 16));
  v.z = (int)((uint32_t)f2bf(f1.x) | ((uint32_t)f2bf(f1.y) << 16));
  v.w = (int)((uint32_t)f2bf(f1.z) | ((uint32_t)f2bf(f1.w) << 16));
  return v;
}

// =====================================================================
// Phase 1: split-K GEMM  hp[s][g][b] = sum_{k in split s} W[g,k] * z[b,k]
// A-operand = W rows (m=group), B-operand = z rows (n=batch) so the MFMA
// D layout (row=q*4+reg=group, col=lane&15=batch) gives b-contiguous stores.
// b_fc skipped: cancels under training-mode batchnorm.
// =====================================================================
__global__ __launch_bounds__(256, 4) void gemm_splitk_kernel(
    const float* __restrict__ zp, const float* __restrict__ wp,
    float* __restrict__ hp) {
  const int tid = threadIdx.x;
  const int g0  = blockIdx.x * GT;
  const int s   = blockIdx.y;               // k-split id
  const int kbase = s * 512;
  const int klen  = (s < 3) ? 512 : (LAT - 3 * 512);  // 464 for s=3

  // LDS tiles, row stride 64 bf16 (128 B), 16B-chunk XOR-by-row swizzle.
  __shared__ ushort As[GT * BK];        //  8 KB (W tile)
  __shared__ ushort Bs[BATCH * BK];     // 16 KB (z tile)

  const int lane = tid & 63;
  const int w    = tid >> 6;
  const int wm   = w & 1;      // group half: +wm*32
  const int wn   = w >> 1;     // batch half: +wn*64
  const int q    = lane >> 4;
  const int cl   = lane & 15;

  f32x4 acc[2][4];
  const f32x4 vzero = {0.f, 0.f, 0.f, 0.f};
#pragma unroll
  for (int i = 0; i < 2; ++i)
#pragma unroll
    for (int j = 0; j < 4; ++j) acc[i][j] = vzero;

  for (int it = 0; it < 8; ++it) {      // 8 * 64 = 512 >= klen
    const int k0 = it * BK;
    __syncthreads();

    // ---- stage A (W tile): 64 rows x 8 chunks = 512 chunks, 2/thread ----
#pragma unroll
    for (int i = 0; i < 2; ++i) {
      int c = i * 256 + tid;
      int r = c >> 3, sc = c & 7;
      int lk = k0 + sc * 8;
      int g  = g0 + r;
      int4 v = make_int4(0, 0, 0, 0);
      if (lk < klen && g < NG)
        v = pack8(wp + (size_t)g * LAT + kbase + lk);
      *(int4*)&As[r * BK + ((sc ^ (r & 7)) << 3)] = v;
    }
    // ---- stage B (z tile): 128 rows x 8 chunks = 1024 chunks, 4/thread ----
#pragma unroll
    for (int i = 0; i < 4; ++i) {
      int c = i * 256 + tid;
      int r = c >> 3, sc = c & 7;
      int lk = k0 + sc * 8;
      int4 v = make_int4(0, 0, 0, 0);
      if (lk < klen)
        v = pack8(zp + (size_t)r * LAT + kbase + lk);
      *(int4*)&Bs[r * BK + ((sc ^ (r & 7)) << 3)] = v;
    }
    __syncthreads();

#pragma unroll
    for (int kk = 0; kk < 2; ++kk) {
      int sc = kk * 4 + q;
      bf16x8 af[2], bfr[4];
#pragma unroll
      for (int mt = 0; mt < 2; ++mt) {
        int ra = wm * 32 + mt * 16 + cl;
        af[mt] = *(const bf16x8*)&As[ra * BK + ((sc ^ (ra & 7)) << 3)];
      }
#pragma unroll
      for (int nt = 0; nt < 4; ++nt) {
        int rb = wn * 64 + nt * 16 + cl;
        bfr[nt] = *(const bf16x8*)&Bs[rb * BK + ((sc ^ (rb & 7)) << 3)];
      }
#pragma unroll
      for (int mt = 0; mt < 2; ++mt)
#pragma unroll
        for (int nt = 0; nt < 4; ++nt)
          acc[mt][nt] = __builtin_amdgcn_mfma_f32_16x16x32_bf16(
              af[mt], bfr[nt], acc[mt][nt], 0, 0, 0);
    }
  }

  // ---- store partial h^T: hp[s][g][b], b contiguous ----
  float* base = hp + (size_t)s * NG * BATCH;
#pragma unroll
  for (int mt = 0; mt < 2; ++mt) {
#pragma unroll
    for (int r = 0; r < 4; ++r) {
      int g = g0 + wm * 32 + mt * 16 + q * 4 + r;
      if (g < NG) {
#pragma unroll
        for (int nt = 0; nt < 4; ++nt) {
          int b = wn * 64 + nt * 16 + cl;
          base[(size_t)g * BATCH + b] = acc[mt][nt][r];
        }
      }
    }
  }
}

// =====================================================================
// Phase 2a: per-group BN stats -> scale/shift. One 32-lane half-wave per
// group; lanes hold 4 batch elements each (float4), summed over 4 k-splits.
// =====================================================================
__global__ __launch_bounds__(256, 4) void stats_kernel(
    const float* __restrict__ hp, const float* __restrict__ gammap,
    const float* __restrict__ betap, float* __restrict__ scalep,
    float* __restrict__ shiftp) {
  const int tid = threadIdx.x;
  const int g   = blockIdx.x * 8 + (tid >> 5);
  const int l32 = tid & 31;

  float4 hv = make_float4(0.f, 0.f, 0.f, 0.f);
#pragma unroll
  for (int s = 0; s < KSPL; ++s) {
    float4 v = *(const float4*)(hp + ((size_t)s * NG + g) * BATCH + l32 * 4);
    hv.x += v.x; hv.y += v.y; hv.z += v.z; hv.w += v.w;
  }
  float sm = hv.x + hv.y + hv.z + hv.w;
  float sq = hv.x * hv.x + hv.y * hv.y + hv.z * hv.z + hv.w * hv.w;
#pragma unroll
  for (int m = 1; m < 32; m <<= 1) {
    sm += __shfl_xor(sm, m);
    sq += __shfl_xor(sq, m);
  }
  if (l32 == 0) {
    float mean = sm * (1.f / 128.f);
    float var  = sq * (1.f / 128.f) - mean * mean;
    var = (var < 0.f) ? 0.f : var;
    float inv   = __builtin_amdgcn_rsqf(var + EPSV);
    float scale = inv * gammap[g];
    scalep[g] = scale;
    shiftp[g] = betap[g] - mean * scale;
  }
}

// =====================================================================
// Phase 2b: expand. 32 lanes per group, each lane 4 batches x 20 outputs.
// Block covers 8 groups x all 128 batches -> owns aligned 640-B output runs
// per batch row (no partial cache lines).
// =====================================================================
__global__ __launch_bounds__(256, 4) void expand_kernel(
    const float* __restrict__ hp, const float* __restrict__ scalep,
    const float* __restrict__ shiftp, const float* __restrict__ convwp,
    const float* __restrict__ convbp, float* __restrict__ out) {
  const int tid = threadIdx.x;
  const int g   = blockIdx.x * 8 + (tid >> 5);
  const int bc  = (tid & 31) * 4;

  float4 hv = make_float4(0.f, 0.f, 0.f, 0.f);
#pragma unroll
  for (int s = 0; s < KSPL; ++s) {
    float4 v = *(const float4*)(hp + ((size_t)s * NG + g) * BATCH + bc);
    hv.x += v.x; hv.y += v.y; hv.z += v.z; hv.w += v.w;
  }

  const float scale = scalep[g];
  const float shift = shiftp[g];
  const float cb    = convbp[g];
  float wv[KW];
  {
    const float4* pw = (const float4*)(convwp + (size_t)g * KW);
#pragma unroll
    for (int j = 0; j < 5; ++j) {
      float4 f = pw[j];
      wv[4 * j] = f.x; wv[4 * j + 1] = f.y;
      wv[4 * j + 2] = f.z; wv[4 * j + 3] = f.w;
    }
  }

  float hb[4] = {hv.x, hv.y, hv.z, hv.w};
#pragma unroll
  for (int i = 0; i < 4; ++i) {
    float h = hb[i] * scale + shift;
    h = fmaxf(h, h * 0.1f);  // leaky(0.1)
    float4 ov[5];
#pragma unroll
    for (int j = 0; j < 5; ++j) {
      float y0 = h * wv[4 * j]     + cb;
      float y1 = h * wv[4 * j + 1] + cb;
      float y2 = h * wv[4 * j + 2] + cb;
      float y3 = h * wv[4 * j + 3] + cb;
      y0 = fmaxf(y0, y0 * 0.1f);
      y1 = fmaxf(y1, y1 * 0.1f);
      y2 = fmaxf(y2, y2 * 0.1f);
      y3 = fmaxf(y3, y3 * 0.1f);
      ov[j].x = __builtin_amdgcn_rcpf(1.f + exp2f(y0 * -1.44269504f));
      ov[j].y = __builtin_amdgcn_rcpf(1.f + exp2f(y1 * -1.44269504f));
      ov[j].z = __builtin_amdgcn_rcpf(1.f + exp2f(y2 * -1.44269504f));
      ov[j].w = __builtin_amdgcn_rcpf(1.f + exp2f(y3 * -1.44269504f));
    }
    float4* po = (float4*)(out + (size_t)(bc + i) * OUTW + (size_t)g * KW);
#pragma unroll
    for (int j = 0; j < 5; ++j) po[j] = ov[j];
  }
}

// =====================================================================
// Fallback: round-2 fused kernel (used only if ws is too small).
// =====================================================================
__global__ __launch_bounds__(256, 2) void fused_decoder_kernel(
    const float* __restrict__ zp, const float* __restrict__ wp,
    const float* __restrict__ gammap, const float* __restrict__ betap,
    const float* __restrict__ convwp, const float* __restrict__ convbp,
    float* __restrict__ out) {
  const int tid = threadIdx.x;
  const int g0  = blockIdx.x * 32;

  __shared__ ushort As[BATCH * BK];
  __shared__ ushort Bs[32 * BK];
  __shared__ float statS[2][2][16];
  __shared__ float statQ[2][2][16];

  const int lane = tid & 63;
  const int w    = tid >> 6;
  const int wm   = w & 1;
  const int wn   = w >> 1;
  const int q    = lane >> 4;
  const int cl   = lane & 15;

  f32x4 acc[4];
  const f32x4 vzero = {0.f, 0.f, 0.f, 0.f};
#pragma unroll
  for (int i = 0; i < 4; ++i) acc[i] = vzero;

  for (int it = 0; it < 32; ++it) {
    const int k0 = it * BK;
    __syncthreads();
#pragma unroll
    for (int i = 0; i < 4; ++i) {
      int c = i * 256 + tid;
      int r = c >> 3, sc = c & 7;
      int gk = k0 + sc * 8;
      int4 v = make_int4(0, 0, 0, 0);
      if (gk < LAT) v = pack8(zp + (size_t)r * LAT + gk);
      *(int4*)&As[r * BK + ((sc ^ (r & 7)) << 3)] = v;
    }
    {
      int r = tid >> 3, sc = tid & 7;
      int g  = g0 + r;
      int gk = k0 + sc * 8;
      int4 v = make_int4(0, 0, 0, 0);
      if (gk < LAT && g < NG) v = pack8(wp + (size_t)g * LAT + gk);
      *(int4*)&Bs[r * BK + ((sc ^ (r & 7)) << 3)] = v;
    }
    __syncthreads();
#pragma unroll
    for (int kk = 0; kk < 2; ++kk) {
      int sc = kk * 4 + q;
      bf16x8 af[4], bfr;
#pragma unroll
      for (int mt = 0; mt < 4; ++mt) {
        int ra = wm * 64 + mt * 16 + cl;
        af[mt] = *(const bf16x8*)&As[ra * BK + ((sc ^ (ra & 7)) << 3)];
      }
      {
        int rb = wn * 16 + cl;
        bfr = *(const bf16x8*)&Bs[rb * BK + ((sc ^ (rb & 7)) << 3)];
      }
#pragma unroll
      for (int mt = 0; mt < 4; ++mt)
        acc[mt] = __builtin_amdgcn_mfma_f32_16x16x32_bf16(af[mt], bfr,
                                                          acc[mt], 0, 0, 0);
    }
  }

  float s = 0.f, ss = 0.f;
#pragma unroll
  for (int mt = 0; mt < 4; ++mt)
#pragma unroll
    for (int r = 0; r < 4; ++r) {
      float v = acc[mt][r];
      s += v; ss += v * v;
    }
  s += __shfl_xor(s, 16); ss += __shfl_xor(ss, 16);
  s += __shfl_xor(s, 32); ss += __shfl_xor(ss, 32);
  if (q == 0) { statS[wm][wn][cl] = s; statQ[wm][wn][cl] = ss; }
  __syncthreads();

  const int gcol = g0 + wn * 16 + cl;
  const int gc   = (gcol < NG) ? gcol : (NG - 1);
  float S = statS[0][wn][cl] + statS[1][wn][cl];
  float Q = statQ[0][wn][cl] + statQ[1][wn][cl];
  float mean = S * (1.f / 128.f);
  float var  = Q * (1.f / 128.f) - mean * mean;
  var = (var < 0.f) ? 0.f : var;
  float inv = __builtin_amdgcn_rsqf(var + EPSV);
  float ga = gammap[gc], be = betap[gc], cb = convbp[gc];
  float wv[KW];
  {
    const float4* pw = (const float4*)(convwp + (size_t)gc * KW);
#pragma unroll
    for (int j = 0; j < 5; ++j) {
      float4 f = pw[j];
      wv[4 * j] = f.x; wv[4 * j + 1] = f.y;
      wv[4 * j + 2] = f.z; wv[4 * j + 3] = f.w;
    }
  }
  float scale = inv * ga;
  float shift = be - mean * scale;
  const bool ok = (gcol < NG);
#pragma unroll
  for (int mt = 0; mt < 4; ++mt) {
#pragma unroll
    for (int r = 0; r < 4; ++r) {
      float h = acc[mt][r] * scale + shift;
      h = fmaxf(h, h * 0.1f);
      int b = wm * 64 + mt * 16 + q * 4 + r;
      float4 ov[5];
#pragma unroll
      for (int j = 0; j < 5; ++j) {
        float y0 = h * wv[4 * j]     + cb;
        float y1 = h * wv[4 * j + 1] + cb;
        float y2 = h * wv[4 * j + 2] + cb;
        float y3 = h * wv[4 * j + 3] + cb;
        y0 = fmaxf(y0, y0 * 0.1f);
        y1 = fmaxf(y1, y1 * 0.1f);
        y2 = fmaxf(y2, y2 * 0.1f);
        y3 = fmaxf(y3, y3 * 0.1f);
        ov[j].x = __builtin_amdgcn_rcpf(1.f + exp2f(y0 * -1.44269504f));
        ov[j].y = __builtin_amdgcn_rcpf(1.f + exp2f(y1 * -1.44269504f));
        ov[j].z = __builtin_amdgcn_rcpf(1.f + exp2f(y2 * -1.44269504f));
        ov[j].w = __builtin_amdgcn_rcpf(1.f + exp2f(y3 * -1.44269504f));
      }
      if (ok) {
        float4* po = (float4*)(out + (size_t)b * OUTW + (size_t)gcol * KW);
#pragma unroll
        for (int j = 0; j < 5; ++j) po[j] = ov[j];
      }
    }
  }
}

extern "C" void kernel_launch(void* const* d_in, const int* in_sizes, int n_in,
                              void* d_out, int out_size, void* d_ws, size_t ws_size,
                              hipStream_t stream) {
  const float* z     = (const float*)d_in[0];
  const float* W     = (const float*)d_in[1];
  // d_in[2] = b_fc: unused — cancels under training-mode batchnorm
  const float* gamma = (const float*)d_in[3];
  const float* beta  = (const float*)d_in[4];
  const float* convw = (const float*)d_in[5];
  const float* convb = (const float*)d_in[6];
  float* out = (float*)d_out;

  const size_t hp_elems = (size_t)KSPL * NG * BATCH;           // 5,120,000
  const size_t need = (hp_elems + 2 * NG) * sizeof(float);     // ~20.6 MB

  if (ws_size >= need) {
    float* hp     = (float*)d_ws;
    float* scalep = hp + hp_elems;
    float* shiftp = scalep + NG;

    dim3 g1((NG + GT - 1) / GT, KSPL);     // 157 x 4 = 628 blocks
    gemm_splitk_kernel<<<g1, 256, 0, stream>>>(z, W, hp);
    stats_kernel<<<NG / 8, 256, 0, stream>>>(hp, gamma, beta, scalep, shiftp);
    expand_kernel<<<NG / 8, 256, 0, stream>>>(hp, scalep, shiftp, convw,
                                              convb, out);
  } else {
    fused_decoder_kernel<<<(NG + 31) / 32, 256, 0, stream>>>(
        z, W, gamma, beta, convw, convb, out);
  }
}